// Round 22
// baseline (378.284 us; speedup 1.0000x reference)
//
#include <hip/hip_runtime.h>
#include <hip/hip_bf16.h>

#define E_EDGES 500000
#define NN 50000

typedef unsigned short u16;
typedef __attribute__((ext_vector_type(8))) short s16x8;
typedef __attribute__((ext_vector_type(4))) float f32x4;

#define BAR() __builtin_amdgcn_s_barrier()
#define SCHED0() __builtin_amdgcn_sched_barrier(0)
#define WAITLGKM0() asm volatile("s_waitcnt lgkmcnt(0)" ::: "memory")

__device__ __forceinline__ short f2bf(float f) {
    unsigned u = __builtin_bit_cast(unsigned, f);
    u += 0x7fffu + ((u >> 16) & 1u);
    return (short)(u >> 16);
}

__device__ __forceinline__ float lrelu(float x) { return x > 0.0f ? x : 0.01f * x; }

// packed fp32x8 -> bf16x8 via v_cvt_pk_bf16_f32
__device__ __forceinline__ s16x8 cvt8(float4 lo, float4 hi) {
    union { s16x8 v; __hip_bfloat162 h[4]; } u;
    u.h[0] = __float22bfloat162_rn(make_float2(lo.x, lo.y));
    u.h[1] = __float22bfloat162_rn(make_float2(lo.z, lo.w));
    u.h[2] = __float22bfloat162_rn(make_float2(hi.x, hi.y));
    u.h[3] = __float22bfloat162_rn(make_float2(hi.z, hi.w));
    return u.v;
}

// ---- weight prep: WT[g][n][k] = bf16(W_g[k][n]), g in {src, tgt, edge} ----
__global__ void kprep(const float* __restrict__ Wsrc, const float* __restrict__ Wtgt,
                      const float* __restrict__ Wedge, u16* __restrict__ WT) {
    int i = blockIdx.x * 256 + threadIdx.x;
    if (i >= 3 * 16384) return;
    int g = i >> 14, nk = i & 16383, n = nk >> 7, k = nk & 127;
    const float* W = (g == 0) ? Wsrc : (g == 1) ? Wtgt : Wedge;
    WT[i] = (u16)f2bf(W[k * 128 + n]);
}

// ---- K1: SINGLE-PHASE, M=32. All 3 matrices staged in ONE batch
// (ra[6][2] = 48 VGPR -> lottery-safe), one commit + one barrier per tile,
// 48 MFMAs/wave with B resident in VGPR (96). Wave wv owns head wv.
// Per tile: 1 drain + 2 barriers (vs 3 drains + 7 barriers in champion). ----
__global__ __launch_bounds__(256, 2) void k1(
    const float* __restrict__ recv, const float* __restrict__ send,
    const float* __restrict__ eattr, const int* __restrict__ sidx,
    const u16* __restrict__ WT, const float* __restrict__ attn,
    float* __restrict__ ez, float* __restrict__ denom)
{
    __shared__ u16 lds[3][32][136];    // 26112 B
    __shared__ float smEz[32][4];      // 512 B
    const int tid = threadIdx.x;
    const int lane = tid & 63, wv = tid >> 6;
    const int l15 = lane & 15, lg = (lane >> 4) & 3;
    const int row0 = blockIdx.x * 32;

    const float* Xg[3] = {send, eattr, recv};
    const int bgoff[3] = {0, 2 * 16384, 1 * 16384};  // Wsrc, Wedge, Wtgt

    // B fragments resident in VGPR (96): bfr[g][kk][nn], nfrag = 2*wv + nn
    s16x8 bfr[3][4][2];
#pragma unroll
    for (int g = 0; g < 3; ++g)
#pragma unroll
        for (int kk = 0; kk < 4; ++kk)
#pragma unroll
            for (int nn = 0; nn < 2; ++nn)
                bfr[g][kk][nn] = *(const s16x8*)(WT + bgoff[g] +
                    ((wv * 2 + nn) * 16 + l15) * 128 + kk * 32 + lg * 8);

    const float av0 = attn[(wv * 2 + 0) * 16 + l15];
    const float av1 = attn[(wv * 2 + 1) * 16 + l15];

    // stage: 3 mats x 32 rows x 16 granules = 1536 chunks of 32B, 6/thread
    float4 ra[6][2];
#pragma unroll
    for (int q = 0; q < 6; ++q) {
        int idx = tid + 256 * q;             // 0..1535
        int mat = idx >> 9, rem = idx & 511;
        int row = rem >> 4, gcol = (rem & 15) * 8;
        int ge = min(row0 + row, E_EDGES - 1);
        const float* p = Xg[mat] + (size_t)ge * 128 + gcol;
        ra[q][0] = *(const float4*)p;
        ra[q][1] = *(const float4*)(p + 4);
    }
    SCHED0();
#pragma unroll
    for (int q = 0; q < 6; ++q) {
        int idx = tid + 256 * q;
        int mat = idx >> 9, rem = idx & 511;
        *(s16x8*)&lds[mat][rem >> 4][(rem & 15) * 8] = cvt8(ra[q][0], ra[q][1]);
    }
    WAITLGKM0();
    BAR();

    f32x4 acc[2][2];
#pragma unroll
    for (int m = 0; m < 2; ++m)
#pragma unroll
        for (int nn = 0; nn < 2; ++nn) acc[m][nn] = (f32x4){0.f, 0.f, 0.f, 0.f};

    // 48 MFMAs/wave: one ds_read feeds 2 MFMAs
#pragma unroll
    for (int g = 0; g < 3; ++g) {
#pragma unroll
        for (int kk = 0; kk < 4; ++kk) {
            int k0 = kk * 32 + lg * 8;
#pragma unroll
            for (int m = 0; m < 2; ++m) {
                s16x8 a = *(const s16x8*)&lds[g][m * 16 + l15][k0];
                acc[m][0] = __builtin_amdgcn_mfma_f32_16x16x32_bf16(a, bfr[g][kk][0], acc[m][0], 0, 0, 0);
                acc[m][1] = __builtin_amdgcn_mfma_f32_16x16x32_bf16(a, bfr[g][kk][1], acc[m][1], 0, 0, 0);
            }
        }
    }

    // epilogue: z for head wv over 32 rows; coalesced store
#pragma unroll
    for (int m = 0; m < 2; ++m) {
        float part[4];
#pragma unroll
        for (int j = 0; j < 4; ++j)
            part[j] = lrelu(acc[m][0][j]) * av0 + lrelu(acc[m][1][j]) * av1;
#pragma unroll
        for (int off = 1; off < 16; off <<= 1) {
#pragma unroll
            for (int j = 0; j < 4; ++j) part[j] += __shfl_xor(part[j], off, 64);
        }
        if (l15 == 0) {
#pragma unroll
            for (int j = 0; j < 4; ++j)
                smEz[m * 16 + lg * 4 + j][wv] = __expf(part[j]);
        }
    }
    __syncthreads();
    if (tid < 128) {
        int row = tid >> 2, h = tid & 3;
        int r = row0 + row;
        float v = smEz[row][h];
        if (r < E_EDGES) {
            ez[(size_t)r * 4 + h] = v;
            int s = sidx[r];
            atomicAdd(&denom[(size_t)s * 4 + h], v);
        }
    }
}

// ---- K2: R17/R19 proven structure (M=64, 3 blocks/CU, one sync), a = ez/denom fused ----
__global__ __launch_bounds__(256, 2) void k2(
    const float* __restrict__ recv, const int* __restrict__ ridx,
    const int* __restrict__ sidx, const u16* __restrict__ WTt,
    const float* __restrict__ ez, const float* __restrict__ denom,
    float* __restrict__ out0, float* __restrict__ out1)
{
    __shared__ u16 ldsA[64][136];      // 17408 B
    __shared__ u16 ldsB[128][136];     // 34816 B
    const int tid = threadIdx.x;
    const int lane = tid & 63, wv = tid >> 6;   // 4 waves x 16 rows
    const int l15 = lane & 15, lg = (lane >> 4) & 3;
    const int row0 = blockIdx.x * 64;

    float4 ra[4][2];
#pragma unroll
    for (int q = 0; q < 4; ++q) {
        int idx = tid + 256 * q;
        int row = idx >> 4, gcol = (idx & 15) * 8;
        int ge = min(row0 + row, E_EDGES - 1);
        const float* p = recv + (size_t)ge * 128 + gcol;
        ra[q][0] = *(const float4*)p;
        ra[q][1] = *(const float4*)(p + 4);
    }
    s16x8 rb[8];
#pragma unroll
    for (int q = 0; q < 8; ++q) {
        int idx = tid + 256 * q;
        rb[q] = *(const s16x8*)(WTt + (idx >> 4) * 128 + (idx & 15) * 8);
    }
#pragma unroll
    for (int q = 0; q < 4; ++q) {
        int idx = tid + 256 * q;
        *(s16x8*)&ldsA[idx >> 4][(idx & 15) * 8] = cvt8(ra[q][0], ra[q][1]);
    }
#pragma unroll
    for (int q = 0; q < 8; ++q) {
        int idx = tid + 256 * q;
        *(s16x8*)&ldsB[idx >> 4][(idx & 15) * 8] = rb[q];
    }
    __syncthreads();

    f32x4 acc[8];
#pragma unroll
    for (int n = 0; n < 8; ++n) acc[n] = (f32x4){0.f, 0.f, 0.f, 0.f};

#pragma unroll
    for (int kk = 0; kk < 4; ++kk) {
        int k0 = kk * 32 + lg * 8;
        s16x8 a = *(const s16x8*)&ldsA[wv * 16 + l15][k0];
#pragma unroll
        for (int n = 0; n < 8; ++n) {
            s16x8 b = *(const s16x8*)&ldsB[n * 16 + l15][k0];
            acc[n] = __builtin_amdgcn_mfma_f32_16x16x32_bf16(a, b, acc[n], 0, 0, 0);
        }
    }

#pragma unroll
    for (int j = 0; j < 4; ++j) {
        int r = row0 + wv * 16 + lg * 4 + j;
        if (r < E_EDGES) {
            int s = sidx[r];
            float4 ezv = *(const float4*)(ez + (size_t)r * 4);
            float4 dn = *(const float4*)(denom + (size_t)s * 4);
            float a0 = ezv.x / dn.x, a1 = ezv.y / dn.y;
            float a2 = ezv.z / dn.z, a3 = ezv.w / dn.w;
            float lo = 0.25f * (acc[0][j] * a0 + acc[2][j] * a1 +
                                acc[4][j] * a2 + acc[6][j] * a3);
            float hi = 0.25f * (acc[1][j] * a0 + acc[3][j] * a1 +
                                acc[5][j] * a2 + acc[7][j] * a3);
            out1[(size_t)r * 32 + l15] = lo;
            out1[(size_t)r * 32 + 16 + l15] = hi;
            int rv = ridx[r];
            atomicAdd(&out0[(size_t)rv * 32 + l15], lo);
            atomicAdd(&out0[(size_t)rv * 32 + 16 + l15], hi);
        }
    }
}

extern "C" void kernel_launch(void* const* d_in, const int* in_sizes, int n_in,
                              void* d_out, int out_size, void* d_ws, size_t ws_size,
                              hipStream_t stream) {
    const float* recv  = (const float*)d_in[0];
    const float* send  = (const float*)d_in[1];
    const float* eattr = (const float*)d_in[2];
    const int*   sidx  = (const int*)d_in[3];
    const int*   ridx  = (const int*)d_in[4];
    const float* Wsrc  = (const float*)d_in[5];
    const float* Wtgt  = (const float*)d_in[6];
    const float* Wedge = (const float*)d_in[7];
    const float* attn  = (const float*)d_in[8];

    char* ws = (char*)d_ws;
    u16*   WT    = (u16*)ws;                         // 98304 B
    float* ez    = (float*)(ws + 131072);            // 8,000,000 B
    float* denom = (float*)(ws + 131072 + 8000000);  // 800,000 B

    float* out0 = (float*)d_out;                     // [N,32]
    float* out1 = out0 + (size_t)NN * 32;            // [E,32]

    hipMemsetAsync(denom, 0, (size_t)NN * 4 * sizeof(float), stream);
    hipMemsetAsync(out0, 0, (size_t)NN * 32 * sizeof(float), stream);

    kprep<<<192, 256, 0, stream>>>(Wsrc, Wtgt, Wedge, WT);

    int nb1 = (E_EDGES + 31) / 32;   // 15625
    int nb2 = (E_EDGES + 63) / 64;   // 7813
    k1<<<nb1, 256, 0, stream>>>(recv, send, eattr, sidx, WT, attn, ez, denom);
    k2<<<nb2, 256, 0, stream>>>(recv, ridx, sidx, WT + 16384, ez, denom, out0, out1);
}

// Round 23
// 276.250 us; speedup vs baseline: 1.3694x; 1.3694x over previous
//
#include <hip/hip_runtime.h>
#include <hip/hip_bf16.h>

#define E_EDGES 500000
#define NN 50000

typedef unsigned short u16;
typedef __attribute__((ext_vector_type(8))) short s16x8;
typedef __attribute__((ext_vector_type(4))) float f32x4;

#define BAR() __builtin_amdgcn_s_barrier()
#define SCHED0() __builtin_amdgcn_sched_barrier(0)
#define WAITLGKM0() asm volatile("s_waitcnt lgkmcnt(0)" ::: "memory")

__device__ __forceinline__ short f2bf(float f) {
    unsigned u = __builtin_bit_cast(unsigned, f);
    u += 0x7fffu + ((u >> 16) & 1u);
    return (short)(u >> 16);
}

__device__ __forceinline__ float lrelu(float x) { return x > 0.0f ? x : 0.01f * x; }

// packed fp32x8 -> bf16x8 via v_cvt_pk_bf16_f32
__device__ __forceinline__ s16x8 cvt8(float4 lo, float4 hi) {
    union { s16x8 v; __hip_bfloat162 h[4]; } u;
    u.h[0] = __float22bfloat162_rn(make_float2(lo.x, lo.y));
    u.h[1] = __float22bfloat162_rn(make_float2(lo.z, lo.w));
    u.h[2] = __float22bfloat162_rn(make_float2(hi.x, hi.y));
    u.h[3] = __float22bfloat162_rn(make_float2(hi.z, hi.w));
    return u.v;
}

// ---- weight prep: WT[g][n][k] = bf16(W_g[k][n]), g in {src, tgt, edge} ----
__global__ void kprep(const float* __restrict__ Wsrc, const float* __restrict__ Wtgt,
                      const float* __restrict__ Wedge, u16* __restrict__ WT) {
    int i = blockIdx.x * 256 + threadIdx.x;
    if (i >= 3 * 16384) return;
    int g = i >> 14, nk = i & 16383, n = nk >> 7, k = nk & 127;
    const float* W = (g == 0) ? Wsrc : (g == 1) ? Wtgt : Wedge;
    WT[i] = (u16)f2bf(W[k * 128 + n]);
}

// ---- K1 (R19 champion): B resident in VGPRs (96 regs, loaded once),
// 1M x 4N wave split (wave wv owns head wv, all 64 rows).
// ~8 interleaved tiles per block (tile = b + i*1024) amortize the B load and
// keep the device-wide read band compact. Per phase: 4 A-loads + 4 ds_writes
// + 16 ds_reads + 32 MFMA per wave; phase-overlapped staging. ----
__global__ __launch_bounds__(256, 2) void k1(
    const float* __restrict__ recv, const float* __restrict__ send,
    const float* __restrict__ eattr, const int* __restrict__ sidx,
    const u16* __restrict__ WT, const float* __restrict__ attn,
    float* __restrict__ ez, float* __restrict__ denom)
{
    __shared__ u16 ldsA[64][136];      // 17408 B
    __shared__ float smEz[64][4];      // 1 KB
    const int tid = threadIdx.x;
    const int lane = tid & 63, wv = tid >> 6;
    const int l15 = lane & 15, lg = (lane >> 4) & 3;
    const int b = blockIdx.x;

    const float* Xg[3] = {send, eattr, recv};
    const int bgoff[3] = {0, 2 * 16384, 1 * 16384};  // Wsrc, Wedge, Wtgt

    // B fragments resident in VGPR: bfr[g][kk][nn]; nfrag = 2*wv + nn
    s16x8 bfr[3][4][2];
#pragma unroll
    for (int g = 0; g < 3; ++g)
#pragma unroll
        for (int kk = 0; kk < 4; ++kk)
#pragma unroll
            for (int nn = 0; nn < 2; ++nn)
                bfr[g][kk][nn] = *(const s16x8*)(WT + bgoff[g] +
                    ((wv * 2 + nn) * 16 + l15) * 128 + kk * 32 + lg * 8);

    const float av0 = attn[(wv * 2 + 0) * 16 + l15];
    const float av1 = attn[(wv * 2 + 1) * 16 + l15];

    f32x4 acc[4][2];
    float4 ra[4][2];

    auto issueA = [&](const float* X, int tileRow) {
#pragma unroll
        for (int q = 0; q < 4; ++q) {
            int idx = tid + 256 * q;                 // 0..1023
            int row = idx >> 4, gcol = (idx & 15) * 8;
            int ge = min(tileRow + row, E_EDGES - 1);
            const float* p = X + (size_t)ge * 128 + gcol;
            ra[q][0] = *(const float4*)p;
            ra[q][1] = *(const float4*)(p + 4);
        }
    };

    auto commitA = [&]() {
#pragma unroll
        for (int q = 0; q < 4; ++q) {
            int idx = tid + 256 * q;
            *(s16x8*)&ldsA[idx >> 4][(idx & 15) * 8] = cvt8(ra[q][0], ra[q][1]);
        }
    };

    auto mfma_ph = [&](const s16x8 (&bf)[4][2]) {
#pragma unroll
        for (int kk = 0; kk < 4; ++kk) {
            int k0 = kk * 32 + lg * 8;
#pragma unroll
            for (int m = 0; m < 4; ++m) {
                s16x8 a = *(const s16x8*)&ldsA[m * 16 + l15][k0];
                acc[m][0] = __builtin_amdgcn_mfma_f32_16x16x32_bf16(a, bf[kk][0], acc[m][0], 0, 0, 0);
                acc[m][1] = __builtin_amdgcn_mfma_f32_16x16x32_bf16(a, bf[kk][1], acc[m][1], 0, 0, 0);
            }
        }
    };

    const int nt = (b < 645) ? 8 : 7;   // 7813 tiles over 1024 blocks, interleaved
    issueA(Xg[0], b * 64);

    for (int i = 0; i < nt; ++i) {
        const int tile = b + i * 1024;
        const int row0 = tile * 64;

#pragma unroll
        for (int m = 0; m < 4; ++m)
#pragma unroll
            for (int nn = 0; nn < 2; ++nn) acc[m][nn] = (f32x4){0.f, 0.f, 0.f, 0.f};

#pragma unroll
        for (int g = 0; g < 3; ++g) {
            if (g == 1) { mfma_ph(bfr[0]); SCHED0(); }
            if (g == 2) { mfma_ph(bfr[1]); SCHED0(); }
            BAR();                               // all waves done reading prev ldsA
            commitA();                           // vmcnt wait + cvt + ds_write
            if (g < 2) issueA(Xg[g + 1], row0);  // queue next stream behind drain
            else if (i + 1 < nt) issueA(Xg[0], row0 + 65536);  // next tile (+1024*64)
            SCHED0();
            WAITLGKM0();                         // ds_writes drained
            BAR();
        }
        mfma_ph(bfr[2]);                         // phase 2; next tile's loads in flight

        // epilogue: z for head wv over this wave's 64 rows
#pragma unroll
        for (int m = 0; m < 4; ++m) {
            float part[4];
#pragma unroll
            for (int j = 0; j < 4; ++j)
                part[j] = lrelu(acc[m][0][j]) * av0 + lrelu(acc[m][1][j]) * av1;
#pragma unroll
            for (int off = 1; off < 16; off <<= 1) {
#pragma unroll
                for (int j = 0; j < 4; ++j) part[j] += __shfl_xor(part[j], off, 64);
            }
            if (l15 == 0) {
#pragma unroll
                for (int j = 0; j < 4; ++j)
                    smEz[m * 16 + lg * 4 + j][wv] = __expf(part[j]);
            }
        }
        __syncthreads();   // smEz complete; also fences ldsA reads before next commit
        {
            int row = tid >> 2, h = tid & 3;
            int r = row0 + row;
            float v = smEz[row][h];
            if (r < E_EDGES) {
                ez[(size_t)r * 4 + h] = v;
                int s = sidx[r];
                atomicAdd(&denom[(size_t)s * 4 + h], v);
            }
        }
    }
}

// ---- K2: R17 proven structure (M=64, 3 blocks/CU, one sync), a = ez/denom fused ----
__global__ __launch_bounds__(256, 2) void k2(
    const float* __restrict__ recv, const int* __restrict__ ridx,
    const int* __restrict__ sidx, const u16* __restrict__ WTt,
    const float* __restrict__ ez, const float* __restrict__ denom,
    float* __restrict__ out0, float* __restrict__ out1)
{
    __shared__ u16 ldsA[64][136];      // 17408 B
    __shared__ u16 ldsB[128][136];     // 34816 B
    const int tid = threadIdx.x;
    const int lane = tid & 63, wv = tid >> 6;   // 4 waves x 16 rows
    const int l15 = lane & 15, lg = (lane >> 4) & 3;
    const int row0 = blockIdx.x * 64;

    float4 ra[4][2];
#pragma unroll
    for (int q = 0; q < 4; ++q) {
        int idx = tid + 256 * q;
        int row = idx >> 4, gcol = (idx & 15) * 8;
        int ge = min(row0 + row, E_EDGES - 1);
        const float* p = recv + (size_t)ge * 128 + gcol;
        ra[q][0] = *(const float4*)p;
        ra[q][1] = *(const float4*)(p + 4);
    }
    s16x8 rb[8];
#pragma unroll
    for (int q = 0; q < 8; ++q) {
        int idx = tid + 256 * q;
        rb[q] = *(const s16x8*)(WTt + (idx >> 4) * 128 + (idx & 15) * 8);
    }
#pragma unroll
    for (int q = 0; q < 4; ++q) {
        int idx = tid + 256 * q;
        *(s16x8*)&ldsA[idx >> 4][(idx & 15) * 8] = cvt8(ra[q][0], ra[q][1]);
    }
#pragma unroll
    for (int q = 0; q < 8; ++q) {
        int idx = tid + 256 * q;
        *(s16x8*)&ldsB[idx >> 4][(idx & 15) * 8] = rb[q];
    }
    __syncthreads();

    f32x4 acc[8];
#pragma unroll
    for (int n = 0; n < 8; ++n) acc[n] = (f32x4){0.f, 0.f, 0.f, 0.f};

#pragma unroll
    for (int kk = 0; kk < 4; ++kk) {
        int k0 = kk * 32 + lg * 8;
        s16x8 a = *(const s16x8*)&ldsA[wv * 16 + l15][k0];
#pragma unroll
        for (int n = 0; n < 8; ++n) {
            s16x8 b = *(const s16x8*)&ldsB[n * 16 + l15][k0];
            acc[n] = __builtin_amdgcn_mfma_f32_16x16x32_bf16(a, b, acc[n], 0, 0, 0);
        }
    }

#pragma unroll
    for (int j = 0; j < 4; ++j) {
        int r = row0 + wv * 16 + lg * 4 + j;
        if (r < E_EDGES) {
            int s = sidx[r];
            float4 ezv = *(const float4*)(ez + (size_t)r * 4);
            float4 dn = *(const float4*)(denom + (size_t)s * 4);
            float a0 = ezv.x / dn.x, a1 = ezv.y / dn.y;
            float a2 = ezv.z / dn.z, a3 = ezv.w / dn.w;
            float lo = 0.25f * (acc[0][j] * a0 + acc[2][j] * a1 +
                                acc[4][j] * a2 + acc[6][j] * a3);
            float hi = 0.25f * (acc[1][j] * a0 + acc[3][j] * a1 +
                                acc[5][j] * a2 + acc[7][j] * a3);
            out1[(size_t)r * 32 + l15] = lo;
            out1[(size_t)r * 32 + 16 + l15] = hi;
            int rv = ridx[r];
            atomicAdd(&out0[(size_t)rv * 32 + l15], lo);
            atomicAdd(&out0[(size_t)rv * 32 + 16 + l15], hi);
        }
    }
}

extern "C" void kernel_launch(void* const* d_in, const int* in_sizes, int n_in,
                              void* d_out, int out_size, void* d_ws, size_t ws_size,
                              hipStream_t stream) {
    const float* recv  = (const float*)d_in[0];
    const float* send  = (const float*)d_in[1];
    const float* eattr = (const float*)d_in[2];
    const int*   sidx  = (const int*)d_in[3];
    const int*   ridx  = (const int*)d_in[4];
    const float* Wsrc  = (const float*)d_in[5];
    const float* Wtgt  = (const float*)d_in[6];
    const float* Wedge = (const float*)d_in[7];
    const float* attn  = (const float*)d_in[8];

    char* ws = (char*)d_ws;
    u16*   WT    = (u16*)ws;                         // 98304 B
    float* ez    = (float*)(ws + 131072);            // 8,000,000 B
    float* denom = (float*)(ws + 131072 + 8000000);  // 800,000 B

    float* out0 = (float*)d_out;                     // [N,32]
    float* out1 = out0 + (size_t)NN * 32;            // [E,32]

    hipMemsetAsync(denom, 0, (size_t)NN * 4 * sizeof(float), stream);
    hipMemsetAsync(out0, 0, (size_t)NN * 32 * sizeof(float), stream);

    kprep<<<192, 256, 0, stream>>>(Wsrc, Wtgt, Wedge, WT);

    k1<<<1024, 256, 0, stream>>>(recv, send, eattr, sidx, WT, attn, ez, denom);
    int nb2 = (E_EDGES + 63) / 64;   // 7813
    k2<<<nb2, 256, 0, stream>>>(recv, ridx, sidx, WT + 16384, ez, denom, out0, out1);
}